// Round 4
// baseline (443.964 us; speedup 1.0000x reference)
//
#include <hip/hip_runtime.h>

// arHOCA: L=200 positions, Q=21 alphabet, H=128 hidden, B=256 batch.
// x is one-hot => all "x @ W" contractions are gather-sums over idx[b,l].
//
// DCA mask (faithful to reference): mask loop is `for i in range(Q)`, so only
// row-blocks 1..20 / col-blocks 0..19 are active; mask[d,c]=1 iff blk(c)<blk(d).
// => out_dca[b,j] = sum_{l=j/Q+1}^{20} DW[l*Q+idx[b,l], j].
//
// ws layout: idxT [200][256] int (204800B) | h1 [199][256][128] f32 (26083328B)
//            | h2T [199][128][256] f32 (26083328B)  => 52371456 B total.

#define Lc   200
#define Qc   21
#define Hc   128
#define Bc   256
#define LQc  4200
#define LM1c 199

// ---------------- K0: idxT[l][b] = argmax_c x[b,l,c] ----------------
__global__ __launch_bounds__(256) void k_idx(const float* __restrict__ x,
                                             int* __restrict__ idxT) {
    const int l = blockIdx.x;       // 0..199
    const int b = threadIdx.x;      // 0..255
    const float* p = x + ((size_t)b * Lc + l) * Qc;
    int id = 0;
#pragma unroll
    for (int c = 0; c < Qc; ++c) id = (p[c] > 0.5f) ? c : id;
    idxT[l * Bc + b] = id;          // coalesced store
}

// ---------------- K1: DCA gather + bias + out0 (w0+b0) ----------------
// out[b, j] = bias[j] + sum_{l = j/Q+1 .. 20} DW[l*Q+idx[b,l], j]  (+ w0+b0 for j<Q)
__global__ __launch_bounds__(256) void k_dca(const float* __restrict__ DW,
                                             const float* __restrict__ bias,
                                             const float* __restrict__ w0,
                                             const float* __restrict__ b0,
                                             const int* __restrict__ idxT,
                                             float* __restrict__ out) {
    const int b = blockIdx.x / 5, chunk = blockIdx.x % 5;
    const int j0 = chunk * 1024 + threadIdx.x * 4;
    if (j0 >= LQc) return;
    float a[4];
    const float4 bv = *(const float4*)(bias + j0);
    a[0] = bv.x; a[1] = bv.y; a[2] = bv.z; a[3] = bv.w;
    if (j0 < Qc) {
#pragma unroll
        for (int e = 0; e < 4; ++e) {
            int j = j0 + e;
            if (j < Qc) a[e] += w0[j] + b0[j];
        }
    }
    if (j0 < (Qc - 1) * Qc) {
        const int lmin = j0 / Qc + 1;
        for (int l = lmin; l < Qc; ++l) {
            const int iv = idxT[l * Bc + b];
            const float4 v = *(const float4*)(DW + (size_t)(l * Qc + iv) * LQc + j0);
            const int thr = l * Qc;  // contribute iff j < l*Q
            a[0] += (j0     < thr) ? v.x : 0.f;
            a[1] += (j0 + 1 < thr) ? v.y : 0.f;
            a[2] += (j0 + 2 < thr) ? v.z : 0.f;
            a[3] += (j0 + 3 < thr) ? v.w : 0.f;
        }
    }
    float4 o = {a[0], a[1], a[2], a[3]};
    *(float4*)(out + (size_t)b * LQc + j0) = o;
}

// ---------------- K2: direct-gather, LDS-free, deep-pipelined ----------------
// h1[l][b][h] = lrelu(sum_{lp<=l} W1[l, lp*Q+idx[b,lp], h] + b1[l,h])
// Block = (l, 64-batch group), 4 waves; wave covers 16 batches; lane owns
// 8 batches (jb half) x 4 h (hq quad). Per lp: 1 idxT load (coalesced,
// prefetched 1 ahead) + 8 shfl + 8 coalesced 512B row loads (addresses known
// at iter start -> 8-deep VMEM pipeline). XCD-chunked swizzle so the 4 groups
// of one l share an XCD L2; reversed l for load balance.
__global__ __launch_bounds__(256) void k_h1(const float* __restrict__ W1,
                                            const float* __restrict__ b1,
                                            const int* __restrict__ idxT,
                                            float* __restrict__ h1) {
    const int bid = blockIdx.x;                 // 0..799
    const int swz = (bid & 7) * 100 + (bid >> 3);
    if (swz >= 4 * LM1c) return;
    const int l = 198 - (swz >> 2);
    const int g = swz & 3;
    const int t = threadIdx.x;
    const int w = t >> 6, lane = t & 63;
    const int jb = lane >> 5, hq = lane & 31;
    const int base = g * 64 + w * 16;           // wave's batch base

    const float* Wl = W1 + (size_t)l * (LQc * Hc);
    const int myb = base + (lane & 15);

    float acc[8][4];
#pragma unroll
    for (int i = 0; i < 8; ++i)
#pragma unroll
        for (int e = 0; e < 4; ++e) acc[i][e] = 0.f;

    int ia_cur = idxT[myb];                     // lp = 0
    for (int lp = 0; lp <= l; ++lp) {
        const int ia_nxt = (lp < l) ? idxT[(lp + 1) * Bc + myb] : 0;
        const int rowbase = lp * Qc;
        float4 v[8];
#pragma unroll
        for (int i = 0; i < 8; ++i) {
            const int row = rowbase + __shfl(ia_cur, jb * 8 + i);
            v[i] = *(const float4*)(Wl + (size_t)row * Hc + hq * 4);
        }
#pragma unroll
        for (int i = 0; i < 8; ++i) {
            acc[i][0] += v[i].x; acc[i][1] += v[i].y;
            acc[i][2] += v[i].z; acc[i][3] += v[i].w;
        }
        ia_cur = ia_nxt;
    }

    const float4 bb = *(const float4*)(b1 + l * Hc + hq * 4);
    float* outp = h1 + ((size_t)l * Bc + base + jb * 8) * Hc + hq * 4;
#pragma unroll
    for (int i = 0; i < 8; ++i) {
        float4 r;
        r.x = acc[i][0] + bb.x; r.y = acc[i][1] + bb.y;
        r.z = acc[i][2] + bb.z; r.w = acc[i][3] + bb.w;
        r.x = (r.x >= 0.f) ? r.x : 0.1f * r.x;
        r.y = (r.y >= 0.f) ? r.y : 0.1f * r.y;
        r.z = (r.z >= 0.f) ? r.z : 0.1f * r.z;
        r.w = (r.w >= 0.f) ? r.w : 0.1f * r.w;
        *(float4*)(outp + (size_t)i * Hc) = r;   // 512B coalesced per half-wave
    }
}

// ---------------- K3: h2T[l][n][b] = lrelu(sum_k h1[l][b][k] * W2[l][k][n] + b2[l][n]) ----------------
// fp32 tiled GEMM: M=128 (batch half), N=128, K=128 in 8 steps of 16. 8x8 reg tile/thread.
// A-side ([b][k] row-major) is transposed into padded LDS during staging.
__global__ __launch_bounds__(256) void k_h2(const float* __restrict__ h1,
                                            const float* __restrict__ W2,
                                            const float* __restrict__ b2,
                                            float* __restrict__ h2T) {
    const int l = blockIdx.x >> 1;
    const int bbase = (blockIdx.x & 1) * 128;
    const int t = threadIdx.x;
    const int tx = t & 15, ty = t >> 4;
    __shared__ float As[16][132];
    __shared__ float Bs[16][Hc];
    __shared__ float Ts[32][Hc];
    float acc[8][8];
#pragma unroll
    for (int i = 0; i < 8; ++i)
#pragma unroll
        for (int j = 0; j < 8; ++j) acc[i][j] = 0.f;
    const int skk = t >> 4, sms = (t & 15) * 8;
    const int au = t >> 2, av4 = (t & 3) * 4;   // A-stage: m=au(+64), k-quad av4
    const float* h1l = h1 + ((size_t)l * Bc + bbase) * Hc;
    const float* W2l = W2 + (size_t)l * Hc * Hc;
    for (int ks = 0; ks < 8; ++ks) {
        const float4 a0 = *(const float4*)(h1l + (size_t)au * Hc + ks * 16 + av4);
        const float4 a1 = *(const float4*)(h1l + (size_t)(au + 64) * Hc + ks * 16 + av4);
        const int kb = ks * 16 + skk;
        *(float4*)&Bs[skk][sms]     = *(const float4*)(W2l + (size_t)kb * Hc + sms);
        *(float4*)&Bs[skk][sms + 4] = *(const float4*)(W2l + (size_t)kb * Hc + sms + 4);
        As[av4 + 0][au] = a0.x; As[av4 + 1][au] = a0.y;
        As[av4 + 2][au] = a0.z; As[av4 + 3][au] = a0.w;
        As[av4 + 0][au + 64] = a1.x; As[av4 + 1][au + 64] = a1.y;
        As[av4 + 2][au + 64] = a1.z; As[av4 + 3][au + 64] = a1.w;
        __syncthreads();
#pragma unroll
        for (int k = 0; k < 16; ++k) {
            float avr[8], bvr[8];
            *(float4*)&avr[0] = *(const float4*)&As[k][ty * 8];
            *(float4*)&avr[4] = *(const float4*)&As[k][ty * 8 + 4];
            *(float4*)&bvr[0] = *(const float4*)&Bs[k][tx * 8];
            *(float4*)&bvr[4] = *(const float4*)&Bs[k][tx * 8 + 4];
#pragma unroll
            for (int i = 0; i < 8; ++i)
#pragma unroll
                for (int j = 0; j < 8; ++j) acc[i][j] += avr[i] * bvr[j];
        }
        __syncthreads();
    }
    float bz[8];
    *(float4*)&bz[0] = *(const float4*)(b2 + l * Hc + tx * 8);
    *(float4*)&bz[4] = *(const float4*)(b2 + l * Hc + tx * 8 + 4);
    float res[8][8];
#pragma unroll
    for (int i = 0; i < 8; ++i)
#pragma unroll
        for (int j = 0; j < 8; ++j) {
            float v = acc[i][j] + bz[j];
            res[i][j] = (v >= 0.f) ? v : 0.1f * v;
        }
    // transpose-store via LDS in 4 chunks of 32 n-rows: h2T[l][n][bbase+m]
    for (int c = 0; c < 4; ++c) {
        if ((tx >> 2) == c) {
#pragma unroll
            for (int i = 0; i < 8; ++i)
#pragma unroll
                for (int j = 0; j < 8; ++j) Ts[(tx & 3) * 8 + j][ty * 8 + i] = res[i][j];
        }
        __syncthreads();
        const int r = t >> 3, m2 = (t & 7) * 16;
        float* dst = h2T + ((size_t)l * Hc + c * 32 + r) * Bc + bbase + m2;
#pragma unroll
        for (int u = 0; u < 4; ++u) *(float4*)(dst + u * 4) = *(const float4*)&Ts[r][m2 + u * 4];
        __syncthreads();
    }
}

// ---------------- K4: out[b, l+1, q] += sum_k h2T[l][k][b] * Wout[l][k][q] + bout[l][q] ----------------
__global__ __launch_bounds__(128) void k_out(const float* __restrict__ h2T,
                                             const float* __restrict__ Wout,
                                             const float* __restrict__ bout,
                                             float* __restrict__ out) {
    const int l = blockIdx.x >> 1;
    const int bh = blockIdx.x & 1;
    const int t = threadIdx.x;  // 0..127
    __shared__ float wl[Hc * Qc];
    __shared__ float bl[Qc];
    const float* wsrc = Wout + (size_t)l * Hc * Qc;
    for (int i = t; i < Hc * Qc; i += 128) wl[i] = wsrc[i];
    if (t < Qc) bl[t] = bout[l * Qc + t];
    __syncthreads();
    const int b = bh * 128 + t;
    float acc[Qc];
#pragma unroll
    for (int q = 0; q < Qc; ++q) acc[q] = bl[q];
    const float* h2l = h2T + (size_t)l * Hc * Bc + b;
    for (int k = 0; k < Hc; ++k) {
        const float av = h2l[(size_t)k * Bc];
        const float* wr = &wl[k * Qc];
#pragma unroll
        for (int q = 0; q < Qc; ++q) acc[q] += av * wr[q];
    }
    float* op = out + ((size_t)b * Lc + (l + 1)) * Qc;
#pragma unroll
    for (int q = 0; q < Qc; ++q) op[q] += acc[q];
}

extern "C" void kernel_launch(void* const* d_in, const int* in_sizes, int n_in,
                              void* d_out, int out_size, void* d_ws, size_t ws_size,
                              hipStream_t stream) {
    const float* x    = (const float*)d_in[0];
    const float* bias = (const float*)d_in[1];
    const float* DW   = (const float*)d_in[2];
    const float* w0   = (const float*)d_in[3];
    const float* b0   = (const float*)d_in[4];
    const float* W1   = (const float*)d_in[5];
    const float* b1   = (const float*)d_in[6];
    const float* W2   = (const float*)d_in[7];
    const float* b2   = (const float*)d_in[8];
    const float* Wout = (const float*)d_in[9];
    const float* bout = (const float*)d_in[10];
    float* out = (float*)d_out;

    int*   idxT = (int*)d_ws;
    float* h1   = (float*)((char*)d_ws + 204800);
    float* h2T  = (float*)((char*)d_ws + 204800 + 26083328);

    k_idx<<<Lc, 256, 0, stream>>>(x, idxT);
    k_dca<<<Bc * 5, 256, 0, stream>>>(DW, bias, w0, b0, idxT, out);
    k_h1<<<800, 256, 0, stream>>>(W1, b1, idxT, h1);
    k_h2<<<LM1c * 2, 256, 0, stream>>>(h1, W2, b2, h2T);
    k_out<<<LM1c * 2, 128, 0, stream>>>(h2T, Wout, bout, out);
}

// Round 5
// 331.536 us; speedup vs baseline: 1.3391x; 1.3391x over previous
//
#include <hip/hip_runtime.h>

// arHOCA: L=200 positions, Q=21 alphabet, H=128 hidden, B=256 batch.
// x is one-hot => all "x @ W" contractions are gather-sums over idx[b,l].
//
// DCA mask (faithful to reference): mask loop is `for i in range(Q)`, so only
// row-blocks 1..20 / col-blocks 0..19 are active; mask[d,c]=1 iff blk(c)<blk(d).
// => out_dca[b,j] = sum_{l=j/Q+1}^{20} DW[l*Q+idx[b,l], j].
//
// ws layout: idxT [200][256] int (204800B) | h1 [199][256][128] f32 (26083328B)
//            | h2T [199][128][256] f32 (26083328B)  => 52371456 B total.

#define Lc   200
#define Qc   21
#define Hc   128
#define Bc   256
#define LQc  4200
#define LM1c 199

// ---------------- K0: idxT[l][b] = argmax_c x[b,l,c] ----------------
__global__ __launch_bounds__(256) void k_idx(const float* __restrict__ x,
                                             int* __restrict__ idxT) {
    const int l = blockIdx.x;       // 0..199
    const int b = threadIdx.x;      // 0..255
    const float* p = x + ((size_t)b * Lc + l) * Qc;
    int id = 0;
#pragma unroll
    for (int c = 0; c < Qc; ++c) id = (p[c] > 0.5f) ? c : id;
    idxT[l * Bc + b] = id;          // coalesced store
}

// ---------------- K1: DCA gather + bias + out0 (w0+b0) ----------------
// out[b, j] = bias[j] + sum_{l = j/Q+1 .. 20} DW[l*Q+idx[b,l], j]  (+ w0+b0 for j<Q)
__global__ __launch_bounds__(256) void k_dca(const float* __restrict__ DW,
                                             const float* __restrict__ bias,
                                             const float* __restrict__ w0,
                                             const float* __restrict__ b0,
                                             const int* __restrict__ idxT,
                                             float* __restrict__ out) {
    const int b = blockIdx.x / 5, chunk = blockIdx.x % 5;
    const int j0 = chunk * 1024 + threadIdx.x * 4;
    if (j0 >= LQc) return;
    float a[4];
    const float4 bv = *(const float4*)(bias + j0);
    a[0] = bv.x; a[1] = bv.y; a[2] = bv.z; a[3] = bv.w;
    if (j0 < Qc) {
#pragma unroll
        for (int e = 0; e < 4; ++e) {
            int j = j0 + e;
            if (j < Qc) a[e] += w0[j] + b0[j];
        }
    }
    if (j0 < (Qc - 1) * Qc) {
        const int lmin = j0 / Qc + 1;
        for (int l = lmin; l < Qc; ++l) {
            const int iv = idxT[l * Bc + b];
            const float4 v = *(const float4*)(DW + (size_t)(l * Qc + iv) * LQc + j0);
            const int thr = l * Qc;  // contribute iff j < l*Q
            a[0] += (j0     < thr) ? v.x : 0.f;
            a[1] += (j0 + 1 < thr) ? v.y : 0.f;
            a[2] += (j0 + 2 < thr) ? v.z : 0.f;
            a[3] += (j0 + 3 < thr) ? v.w : 0.f;
        }
    }
    float4 o = {a[0], a[1], a[2], a[3]};
    *(float4*)(out + (size_t)b * LQc + j0) = o;
}

// ---------------- K2: direct-gather, 2-deep software pipeline ----------------
// h1[l][b][h] = lrelu(sum_{lp<=l} W1[l, lp*Q+idx[b,lp], h] + b1[l,h])
// Block = (l, 64-batch group); wave = 16 batches; half-wave = 8 batches; lane
// owns 8 batches x 4 h. Ping-pong va/vb (static indexing) keeps 8 loads in
// flight while consuming the previous 8; sched_barrier(0) pins issue order.
// Dummy loads at the tail are in-bounds (row < 4200) and never consumed.
__global__ __launch_bounds__(256, 4) void k_h1(const float* __restrict__ W1,
                                               const float* __restrict__ b1,
                                               const int* __restrict__ idxT,
                                               float* __restrict__ h1) {
    const int bid = blockIdx.x;                 // 0..799
    const int swz = (bid & 7) * 100 + (bid >> 3);
    if (swz >= 4 * LM1c) return;
    const int l = 198 - (swz >> 2);
    const int g = swz & 3;
    const int t = threadIdx.x;
    const int w = t >> 6, lane = t & 63;
    const int jb = lane >> 5, hq = lane & 31;
    const int wbase = g * 64 + w * 16;          // wave's 16 batches
    const int myb = wbase + (lane & 15);

    const float* Wl = W1 + (size_t)l * (LQc * Hc);
    const float* Wq = Wl + hq * 4;

    float acc[8][4];
#pragma unroll
    for (int i = 0; i < 8; ++i)
#pragma unroll
        for (int e = 0; e < 4; ++e) acc[i][e] = 0.f;

    float4 va[8], vb[8];
    int ia0 = idxT[myb];                              // idx[lp=0]
    int ia1 = (l >= 1) ? idxT[Bc + myb] : 0;          // idx[lp=1]

#define ISSUE(dst, lpv, iareg)                                            \
    {                                                                     \
        const int rb_ = (lpv) * Qc;                                       \
        _Pragma("unroll")                                                 \
        for (int i_ = 0; i_ < 8; ++i_) {                                  \
            const int row_ = rb_ + __shfl((iareg), jb * 8 + i_);          \
            dst[i_] = *(const float4*)(Wq + (size_t)row_ * Hc);           \
        }                                                                 \
    }
#define CONSUME(src)                                                      \
    {                                                                     \
        _Pragma("unroll")                                                 \
        for (int i_ = 0; i_ < 8; ++i_) {                                  \
            acc[i_][0] += src[i_].x; acc[i_][1] += src[i_].y;             \
            acc[i_][2] += src[i_].z; acc[i_][3] += src[i_].w;             \
        }                                                                 \
    }

    ISSUE(va, 0, ia0);
    __builtin_amdgcn_sched_barrier(0);

    int lp = 0;
    while (lp + 1 <= l) {
        const int ia2 = (lp + 2 <= l) ? idxT[(lp + 2) * Bc + myb] : 0;
        const int ia3 = (lp + 3 <= l) ? idxT[(lp + 3) * Bc + myb] : 0;
        ISSUE(vb, lp + 1, ia1);                 // real (lp+1 <= l)
        __builtin_amdgcn_sched_barrier(0);
        CONSUME(va);                            // lp
        ISSUE(va, lp + 2, ia2);                 // may be dummy; in-bounds
        __builtin_amdgcn_sched_barrier(0);
        CONSUME(vb);                            // lp+1
        ia1 = ia3;
        lp += 2;
    }
    if (lp == l) {                              // one step left in va
        CONSUME(va);
    }
#undef ISSUE
#undef CONSUME

    const float4 bb = *(const float4*)(b1 + l * Hc + hq * 4);
    float* outp = h1 + ((size_t)l * Bc + wbase + jb * 8) * Hc + hq * 4;
#pragma unroll
    for (int i = 0; i < 8; ++i) {
        float4 r;
        r.x = acc[i][0] + bb.x; r.y = acc[i][1] + bb.y;
        r.z = acc[i][2] + bb.z; r.w = acc[i][3] + bb.w;
        r.x = (r.x >= 0.f) ? r.x : 0.1f * r.x;
        r.y = (r.y >= 0.f) ? r.y : 0.1f * r.y;
        r.z = (r.z >= 0.f) ? r.z : 0.1f * r.z;
        r.w = (r.w >= 0.f) ? r.w : 0.1f * r.w;
        *(float4*)(outp + (size_t)i * Hc) = r;   // 512B coalesced per half-wave
    }
}

// ---------------- K3: h2T[l][n][b] = lrelu(sum_k h1[l][b][k] * W2[l][k][n] + b2[l][n]) ----------------
// fp32 tiled GEMM: M=128 (batch half), N=128, K=128 in 8 steps of 16. 8x8 reg tile/thread.
// A-side ([b][k] row-major) is transposed into padded LDS during staging.
__global__ __launch_bounds__(256) void k_h2(const float* __restrict__ h1,
                                            const float* __restrict__ W2,
                                            const float* __restrict__ b2,
                                            float* __restrict__ h2T) {
    const int l = blockIdx.x >> 1;
    const int bbase = (blockIdx.x & 1) * 128;
    const int t = threadIdx.x;
    const int tx = t & 15, ty = t >> 4;
    __shared__ float As[16][132];
    __shared__ float Bs[16][Hc];
    __shared__ float Ts[32][Hc];
    float acc[8][8];
#pragma unroll
    for (int i = 0; i < 8; ++i)
#pragma unroll
        for (int j = 0; j < 8; ++j) acc[i][j] = 0.f;
    const int skk = t >> 4, sms = (t & 15) * 8;
    const int au = t >> 2, av4 = (t & 3) * 4;   // A-stage: m=au(+64), k-quad av4
    const float* h1l = h1 + ((size_t)l * Bc + bbase) * Hc;
    const float* W2l = W2 + (size_t)l * Hc * Hc;
    for (int ks = 0; ks < 8; ++ks) {
        const float4 a0 = *(const float4*)(h1l + (size_t)au * Hc + ks * 16 + av4);
        const float4 a1 = *(const float4*)(h1l + (size_t)(au + 64) * Hc + ks * 16 + av4);
        const int kb = ks * 16 + skk;
        *(float4*)&Bs[skk][sms]     = *(const float4*)(W2l + (size_t)kb * Hc + sms);
        *(float4*)&Bs[skk][sms + 4] = *(const float4*)(W2l + (size_t)kb * Hc + sms + 4);
        As[av4 + 0][au] = a0.x; As[av4 + 1][au] = a0.y;
        As[av4 + 2][au] = a0.z; As[av4 + 3][au] = a0.w;
        As[av4 + 0][au + 64] = a1.x; As[av4 + 1][au + 64] = a1.y;
        As[av4 + 2][au + 64] = a1.z; As[av4 + 3][au + 64] = a1.w;
        __syncthreads();
#pragma unroll
        for (int k = 0; k < 16; ++k) {
            float avr[8], bvr[8];
            *(float4*)&avr[0] = *(const float4*)&As[k][ty * 8];
            *(float4*)&avr[4] = *(const float4*)&As[k][ty * 8 + 4];
            *(float4*)&bvr[0] = *(const float4*)&Bs[k][tx * 8];
            *(float4*)&bvr[4] = *(const float4*)&Bs[k][tx * 8 + 4];
#pragma unroll
            for (int i = 0; i < 8; ++i)
#pragma unroll
                for (int j = 0; j < 8; ++j) acc[i][j] += avr[i] * bvr[j];
        }
        __syncthreads();
    }
    float bz[8];
    *(float4*)&bz[0] = *(const float4*)(b2 + l * Hc + tx * 8);
    *(float4*)&bz[4] = *(const float4*)(b2 + l * Hc + tx * 8 + 4);
    float res[8][8];
#pragma unroll
    for (int i = 0; i < 8; ++i)
#pragma unroll
        for (int j = 0; j < 8; ++j) {
            float v = acc[i][j] + bz[j];
            res[i][j] = (v >= 0.f) ? v : 0.1f * v;
        }
    // transpose-store via LDS in 4 chunks of 32 n-rows: h2T[l][n][bbase+m]
    for (int c = 0; c < 4; ++c) {
        if ((tx >> 2) == c) {
#pragma unroll
            for (int i = 0; i < 8; ++i)
#pragma unroll
                for (int j = 0; j < 8; ++j) Ts[(tx & 3) * 8 + j][ty * 8 + i] = res[i][j];
        }
        __syncthreads();
        const int r = t >> 3, m2 = (t & 7) * 16;
        float* dst = h2T + ((size_t)l * Hc + c * 32 + r) * Bc + bbase + m2;
#pragma unroll
        for (int u = 0; u < 4; ++u) *(float4*)(dst + u * 4) = *(const float4*)&Ts[r][m2 + u * 4];
        __syncthreads();
    }
}

// ---------------- K4: out[b, l+1, q] += sum_k h2T[l][k][b] * Wout[l][k][q] + bout[l][q] ----------------
__global__ __launch_bounds__(128) void k_out(const float* __restrict__ h2T,
                                             const float* __restrict__ Wout,
                                             const float* __restrict__ bout,
                                             float* __restrict__ out) {
    const int l = blockIdx.x >> 1;
    const int bh = blockIdx.x & 1;
    const int t = threadIdx.x;  // 0..127
    __shared__ float wl[Hc * Qc];
    __shared__ float bl[Qc];
    const float* wsrc = Wout + (size_t)l * Hc * Qc;
    for (int i = t; i < Hc * Qc; i += 128) wl[i] = wsrc[i];
    if (t < Qc) bl[t] = bout[l * Qc + t];
    __syncthreads();
    const int b = bh * 128 + t;
    float acc[Qc];
#pragma unroll
    for (int q = 0; q < Qc; ++q) acc[q] = bl[q];
    const float* h2l = h2T + (size_t)l * Hc * Bc + b;
    for (int k = 0; k < Hc; ++k) {
        const float av = h2l[(size_t)k * Bc];
        const float* wr = &wl[k * Qc];
#pragma unroll
        for (int q = 0; q < Qc; ++q) acc[q] += av * wr[q];
    }
    float* op = out + ((size_t)b * Lc + (l + 1)) * Qc;
#pragma unroll
    for (int q = 0; q < Qc; ++q) op[q] += acc[q];
}

extern "C" void kernel_launch(void* const* d_in, const int* in_sizes, int n_in,
                              void* d_out, int out_size, void* d_ws, size_t ws_size,
                              hipStream_t stream) {
    const float* x    = (const float*)d_in[0];
    const float* bias = (const float*)d_in[1];
    const float* DW   = (const float*)d_in[2];
    const float* w0   = (const float*)d_in[3];
    const float* b0   = (const float*)d_in[4];
    const float* W1   = (const float*)d_in[5];
    const float* b1   = (const float*)d_in[6];
    const float* W2   = (const float*)d_in[7];
    const float* b2   = (const float*)d_in[8];
    const float* Wout = (const float*)d_in[9];
    const float* bout = (const float*)d_in[10];
    float* out = (float*)d_out;

    int*   idxT = (int*)d_ws;
    float* h1   = (float*)((char*)d_ws + 204800);
    float* h2T  = (float*)((char*)d_ws + 204800 + 26083328);

    k_idx<<<Lc, 256, 0, stream>>>(x, idxT);
    k_dca<<<Bc * 5, 256, 0, stream>>>(DW, bias, w0, b0, idxT, out);
    k_h1<<<800, 256, 0, stream>>>(W1, b1, idxT, h1);
    k_h2<<<LM1c * 2, 256, 0, stream>>>(h1, W2, b2, h2T);
    k_out<<<LM1c * 2, 128, 0, stream>>>(h2T, Wout, bout, out);
}